// Round 17
// baseline (50.475 us; speedup 1.0000x reference)
//
#include <hip/hip_runtime.h>
#include <hip/hip_bf16.h>
#include <math.h>

typedef float  f32x4  __attribute__((ext_vector_type(4)));
typedef int    v8i    __attribute__((ext_vector_type(8)));
typedef long long i64;

#define N_ROWS 4096
#define E_DIM  256
#define TWO_N  (2 * N_ROWS)
#define BT 128                        /* band tile: 128x128 panels (64 panels)  */
#define KT 128                        /* K-tile: 128 fp8 elements = 128B rows   */
#define NSLOT 65                      /* row-side d=0..32 -> slot d; col-side d -> slot 32+d */
#define SQRT_L 3.798282567081813f     /* sqrt(10*log2(e)): folded so acc = sim*10*log2(e) */
#define SCALE1 127                    /* e8m0 unity scale: 2^(127-127) = 1.0 */

__device__ __forceinline__ void gload_lds16(const void* g, void* l) {
    __builtin_amdgcn_global_load_lds(
        (const __attribute__((address_space(1))) void*)g,
        (__attribute__((address_space(3))) void*)l,
        16, 0, 0);
}

// ---------------- prep: normalize + fold sqrt(10*log2e) + fp8 e4m3 cast ----------------
__global__ __launch_bounds__(256) void prep_kernel(
    const float* __restrict__ tab, const float* __restrict__ ts,
    unsigned char* __restrict__ zn, int* __restrict__ cnt)
{
    const int tid  = threadIdx.x;
    const int wave = tid >> 6, lane = tid & 63;
    const int row  = blockIdx.x * 4 + wave;

    if (blockIdx.x == 0 && tid == 0) cnt[0] = 0;   // re-arm fin ticket every call

    const float* src = row < N_ROWS ? tab + (size_t)row * E_DIM
                                    : ts + (size_t)(row - N_ROWS) * E_DIM;
    const float4 v = *(const float4*)(src + lane * 4);
    float ss = v.x * v.x + v.y * v.y + v.z * v.z + v.w * v.w;
    #pragma unroll
    for (int m = 32; m >= 1; m >>= 1) ss += __shfl_xor(ss, m);
    const float inv = SQRT_L / fmaxf(sqrtf(ss), 1e-8f);
    int p = __builtin_amdgcn_cvt_pk_fp8_f32(v.x * inv, v.y * inv, 0, false);
    p     = __builtin_amdgcn_cvt_pk_fp8_f32(v.z * inv, v.w * inv, p, true);
    *(int*)(zn + (size_t)row * E_DIM + lane * 4) = p;
}

// ---------------- band-symmetric fused sim GEMM, MX-scaled fp8 K=128 ----------------
// grid(64,33): i fast (XCD = i%8 -> fixed A-set), d = band; tile (i, j=(i+d)&63).
// r16 structure frozen; inner loop upgraded to mfma_scale_f32_16x16x128_f8f6f4
// (2.3x fp8 rate, m21): 32 MFMAs/wave vs 128. Unity e8m0 scale (127). Same LDS
// bytes/swizzle: lane packs its four 8B reads into one v8i32 operand. Correct by
// B=A k-permutation symmetry; C/D layout shape-determined (m121-128).
__global__ __launch_bounds__(256, 4) void simloss_kernel(
    const unsigned char* __restrict__ zn,
    const int* __restrict__ labels,
    float* __restrict__ rowExpP,   /* [65][8192] */
    float* __restrict__ rowPosP)   /* [65][8192] */
{
    const int i = blockIdx.x;          // 0..63 row panel
    const int d = blockIdx.y;          // 0..32 band
    if (d == 32 && i >= 32) return;    // half-band: pair {i,i+32} once
    const int j = (i + d) & 63;        // col panel

    const int rb = i * BT;
    const int cb = j * BT;

    __shared__ __align__(16) char ldsS[32768];   // staging A(16K)+B(16K); tables overlay
    __shared__ int labRow[BT];
    __shared__ int labCol[BT];

    char* ldsA = ldsS;
    char* ldsB = ldsS + 16384;

    const int tid  = threadIdx.x;
    const int lane = tid & 63;
    const int wave = tid >> 6;           // 0..3
    const int wr = wave >> 1, wc = wave & 1;
    const int l15 = lane & 15, lg = lane >> 4;

    if (tid < BT)      labRow[tid]      = labels[(rb + tid) & (N_ROWS - 1)];
    else               labCol[tid - BT] = labels[(cb + tid - BT) & (N_ROWS - 1)];

    f32x4 acc[4][4];
    #pragma unroll
    for (int a = 0; a < 4; ++a)
        #pragma unroll
        for (int b = 0; b < 4; ++b) acc[a][b] = (f32x4){0.f, 0.f, 0.f, 0.f};

    #pragma unroll
    for (int kt = 0; kt < E_DIM / KT; ++kt) {   // 2 K-tiles of 128 fp8
        #pragma unroll
        for (int it = 0; it < 4; ++it) {
            const int idx = it * 256 + wave * 64 + lane;  // 16B chunk id 0..1023
            const int row = idx >> 3;                     // 0..127
            const int sch = (idx & 7) ^ (row & 7);
            gload_lds16(zn + (size_t)(rb + row) * E_DIM + kt * KT + sch * 16,
                        ldsA + (it * 256 + wave * 64) * 16);
            gload_lds16(zn + (size_t)(cb + row) * E_DIM + kt * KT + sch * 16,
                        ldsB + (it * 256 + wave * 64) * 16);
        }
        __syncthreads();

        // pack each lane's 4x 8B swizzled reads into one v8i32 K=128 operand
        v8i af[4];
        #pragma unroll
        for (int rf = 0; rf < 4; ++rf) {
            const int r = wr * 64 + rf * 16 + l15;
            #pragma unroll
            for (int ks = 0; ks < 4; ++ks) {
                const int kc = ks * 4 + lg;        // 8B unit 0..15
                const int c  = kc >> 1, h = kc & 1;
                const int2 t = *(const int2*)(ldsA + r * 128 + ((c ^ (r & 7)) << 4) + h * 8);
                af[rf][2 * ks]     = t.x;
                af[rf][2 * ks + 1] = t.y;
            }
        }
        #pragma unroll
        for (int cf = 0; cf < 4; ++cf) {           // B one-at-a-time: VGPR < 128
            const int cc = wc * 64 + cf * 16 + l15;
            v8i bf;
            #pragma unroll
            for (int ks = 0; ks < 4; ++ks) {
                const int kc = ks * 4 + lg;
                const int c  = kc >> 1, h = kc & 1;
                const int2 t = *(const int2*)(ldsB + cc * 128 + ((c ^ (cc & 7)) << 4) + h * 8);
                bf[2 * ks]     = t.x;
                bf[2 * ks + 1] = t.y;
            }
            #pragma unroll
            for (int rf = 0; rf < 4; ++rf)
                acc[rf][cf] = __builtin_amdgcn_mfma_scale_f32_16x16x128_f8f6f4(
                    af[rf], bf, acc[rf][cf], 0, 0, 0, SCALE1, 0, SCALE1);
        }
        __syncthreads();
    }

    // ---- epilogue (r13-frozen): one sweep -> row table + col regs; pos pass ----
    const bool isDiag = (d == 0);
    const bool cross  = (i < 32) != (j < 32);

    float* tblRow = (float*)ldsS;            // [128][44] f32 = 22.5KB (overlay)
    float* tblCol = (float*)(ldsS + 22528);  // [128][12] f32 = 6KB

    int cl[4], clab[4];
    #pragma unroll
    for (int cf = 0; cf < 4; ++cf) {
        cl[cf]   = wc * 64 + cf * 16 + l15;
        clab[cf] = labCol[cl[cf]];
    }

    float colE[4] = {0.f, 0.f, 0.f, 0.f};
    float colP[4] = {0.f, 0.f, 0.f, 0.f};

    #pragma unroll
    for (int rf = 0; rf < 4; ++rf) {
        #pragma unroll
        for (int jj = 0; jj < 4; ++jj) {
            const int rloc = wr * 64 + rf * 16 + lg * 4 + jj;
            const int rlab = labRow[rloc];
            float rowE = 0.f;
            #pragma unroll
            for (int cf = 0; cf < 4; ++cf) {
                const float s = acc[rf][cf][jj];         // = sim * 10*log2(e)
                float e = __builtin_amdgcn_exp2f(s);
                if (isDiag && rloc == cl[cf]) e = 0.f;
                rowE += e;
                colE[cf] += e;
                if (cross && rlab == clab[cf]) colP[cf] += s;
            }
            tblRow[rloc * 44 + wc * 16 + l15] = rowE;
        }
    }
    #pragma unroll
    for (int cf = 0; cf < 4; ++cf)
        tblCol[cl[cf] * 12 + wr * 4 + lg] = colE[cf];

    __syncthreads();

    if (tid < 128) {
        const float* rp = tblRow + tid * 44;
        const int rot = (tid >> 3) & 7;
        float es = 0.f;
        #pragma unroll
        for (int c0 = 0; c0 < 8; ++c0) {
            const int ch = (c0 + rot) & 7;
            f32x4 v = *(const f32x4*)(rp + ch * 4);
            es += v[0] + v[1] + v[2] + v[3];
        }
        rowExpP[(size_t)d * TWO_N + rb + tid] = es;

        if (d > 0) {
            const float* cp = tblCol + tid * 12;
            f32x4 a = *(const f32x4*)(cp);
            f32x4 b = *(const f32x4*)(cp + 4);
            rowExpP[(size_t)(32 + d) * TWO_N + cb + tid] =
                a[0]+a[1]+a[2]+a[3] + b[0]+b[1]+b[2]+b[3];
        }
    }

    if (cross) {
        __syncthreads();
        #pragma unroll
        for (int rf = 0; rf < 4; ++rf) {
            #pragma unroll
            for (int jj = 0; jj < 4; ++jj) {
                const int rloc = wr * 64 + rf * 16 + lg * 4 + jj;
                const int rlab = labRow[rloc];
                float rowP = 0.f;
                #pragma unroll
                for (int cf = 0; cf < 4; ++cf)
                    if (rlab == clab[cf]) rowP += acc[rf][cf][jj];
                tblRow[rloc * 44 + wc * 16 + l15] = rowP;
            }
        }
        #pragma unroll
        for (int cf = 0; cf < 4; ++cf)
            tblCol[cl[cf] * 12 + wr * 4 + lg] = colP[cf];
        __syncthreads();
        if (tid < 128) {
            const float* rp = tblRow + tid * 44;
            const int rot = (tid >> 3) & 7;
            float ps = 0.f;
            #pragma unroll
            for (int c0 = 0; c0 < 8; ++c0) {
                const int ch = (c0 + rot) & 7;
                f32x4 v = *(const f32x4*)(rp + ch * 4);
                ps += v[0] + v[1] + v[2] + v[3];
            }
            rowPosP[(size_t)d * TWO_N + rb + tid] = ps;
            if (d > 0) {
                const float* cp = tblCol + tid * 12;
                f32x4 a = *(const f32x4*)(cp);
                f32x4 b = *(const f32x4*)(cp + 4);
                rowPosP[(size_t)(32 + d) * TWO_N + cb + tid] =
                    a[0]+a[1]+a[2]+a[3] + b[0]+b[1]+b[2]+b[3];
            }
        }
    } else {
        if (tid < 128) {
            rowPosP[(size_t)d * TWO_N + rb + tid] = 0.f;
            if (d > 0) rowPosP[(size_t)(32 + d) * TWO_N + cb + tid] = 0.f;
        }
    }

    // ---- d=32 mirror slots (tiles (j, j+32) for j>=32 are not dispatched) ----
    if (d == 32 && tid < 128) {
        rowExpP[(size_t)64 * TWO_N + rb + tid] = 0.f;
        rowExpP[(size_t)32 * TWO_N + cb + tid] = 0.f;
        rowPosP[(size_t)64 * TWO_N + rb + tid] = 0.f;
        rowPosP[(size_t)32 * TWO_N + cb + tid] = 0.f;
    }
}

// ---------------- finalize (merged): partials reduce + last-block scalar ----------------
__global__ __launch_bounds__(256) void fin_kernel(
    const float* __restrict__ rowExpP, const float* __restrict__ rowPosP,
    const int* __restrict__ labels, double* __restrict__ partial,
    int* __restrict__ cnt, float* __restrict__ out)
{
    __shared__ int hist[128];
    __shared__ double wsum[4];
    const int tid = threadIdx.x;
    if (tid < 128) hist[tid] = 0;
    __syncthreads();
    for (int idx = tid; idx < N_ROWS; idx += 256) atomicAdd(&hist[labels[idx]], 1);
    __syncthreads();

    const int r = blockIdx.x * 256 + tid;  // 0..8191 (grid = 32)
    float es = 0.f;
    #pragma unroll 5
    for (int s = 0; s < NSLOT; ++s) es += rowExpP[(size_t)s * TWO_N + r];
    float ps = 0.f;
    #pragma unroll 5
    for (int s = 0; s < NSLOT; ++s) ps += rowPosP[(size_t)s * TWO_N + r];

    const int lab = labels[r & (N_ROWS - 1)];
    // ps is scaled by 10*log2(e); 10*sim_sum = ps * ln(2)
    double g = ((double)ps * 0.6931471805599453 - (double)N_ROWS * log((double)es))
               / (2.0 * (double)hist[lab]);

    #pragma unroll
    for (int m = 32; m >= 1; m >>= 1) g += __shfl_xor(g, m);
    const int wave = tid >> 6, lane = tid & 63;
    if (lane == 0) wsum[wave] = g;
    __syncthreads();
    if (tid == 0) {
        partial[blockIdx.x] = wsum[0] + wsum[1] + wsum[2] + wsum[3];
        __threadfence();                        // 32 fences, post-traffic: cheap (r15-proven)
        const int t = atomicAdd(&cnt[0], 1);
        if (t == 31) {
            __threadfence();
            double tot = 0.0;
            for (int b = 0; b < 32; ++b) tot += partial[b];   // fixed order: deterministic
            out[0] = (float)(-tot / (double)TWO_N);
        }
    }
}

extern "C" void kernel_launch(void* const* d_in, const int* in_sizes, int n_in,
                              void* d_out, int out_size, void* d_ws, size_t ws_size,
                              hipStream_t stream) {
    const float* tab    = (const float*)d_in[0];
    const float* ts     = (const float*)d_in[1];
    const int*   labels = (const int*)d_in[2];

    char* ws = (char*)d_ws;
    unsigned char* zn = (unsigned char*)ws;                          // 2 MB fp8
    const size_t znBytes = (size_t)TWO_N * E_DIM;
    float* rowExpP = (float*)(ws + znBytes);                         // 2.13 MB [65][8192]
    float* rowPosP = rowExpP + (size_t)NSLOT * TWO_N;                // 2.13 MB [65][8192]
    double* partial = (double*)(rowPosP + (size_t)NSLOT * TWO_N);    // 256 B
    int* cnt = (int*)(partial + 32);                                 // 4 B

    prep_kernel<<<TWO_N / 4, 256, 0, stream>>>(tab, ts, zn, cnt);

    dim3 grid(64, 33);  // i fast (XCD = i%8, fixed A-set); d slow (fixed B-class/band)
    simloss_kernel<<<grid, 256, 0, stream>>>(zn, labels, rowExpP, rowPosP);

    fin_kernel<<<32, 256, 0, stream>>>(rowExpP, rowPosP, labels, partial, cnt, (float*)d_out);
}

// Round 18
// 46.202 us; speedup vs baseline: 1.0925x; 1.0925x over previous
//
#include <hip/hip_runtime.h>
#include <hip/hip_bf16.h>
#include <math.h>

typedef float  f32x4  __attribute__((ext_vector_type(4)));
typedef long long i64;

#define N_ROWS 4096
#define E_DIM  256
#define TWO_N  (2 * N_ROWS)
#define BT 128                        /* band tile: 128x128 panels (64 panels)  */
#define KT 128                        /* K-tile: 128 fp8 elements = 128B rows   */
#define NSLOT 65                      /* row-side d=0..32 -> slot d; col-side d -> slot 32+d */
#define SQRT_L 3.798282567081813f     /* sqrt(10*log2(e)): folded so acc = sim*10*log2(e) */

__device__ __forceinline__ void gload_lds16(const void* g, void* l) {
    __builtin_amdgcn_global_load_lds(
        (const __attribute__((address_space(1))) void*)g,
        (__attribute__((address_space(3))) void*)l,
        16, 0, 0);
}

// ---------------- prep: normalize + fold sqrt(10*log2e) + fp8 e4m3 cast ----------------
__global__ __launch_bounds__(256) void prep_kernel(
    const float* __restrict__ tab, const float* __restrict__ ts,
    unsigned char* __restrict__ zn, int* __restrict__ cnt)
{
    const int tid  = threadIdx.x;
    const int wave = tid >> 6, lane = tid & 63;
    const int row  = blockIdx.x * 4 + wave;

    if (blockIdx.x == 0 && tid == 0) cnt[0] = 0;   // re-arm fin ticket every call

    const float* src = row < N_ROWS ? tab + (size_t)row * E_DIM
                                    : ts + (size_t)(row - N_ROWS) * E_DIM;
    const float4 v = *(const float4*)(src + lane * 4);
    float ss = v.x * v.x + v.y * v.y + v.z * v.z + v.w * v.w;
    #pragma unroll
    for (int m = 32; m >= 1; m >>= 1) ss += __shfl_xor(ss, m);
    const float inv = SQRT_L / fmaxf(sqrtf(ss), 1e-8f);
    // pack 4 fp8 e4m3 (native cvt, OCP on gfx950): bytes[0..3] = x,y,z,w
    int p = __builtin_amdgcn_cvt_pk_fp8_f32(v.x * inv, v.y * inv, 0, false);
    p     = __builtin_amdgcn_cvt_pk_fp8_f32(v.z * inv, v.w * inv, p, true);
    *(int*)(zn + (size_t)row * E_DIM + lane * 4) = p;
}

// ---------------- band-symmetric fused sim GEMM, fp8 e4m3 (r16-proven) ----------------
// grid(64,33): i fast (XCD = i%8 -> fixed A-set), d = band; tile (i, j=(i+d)&63).
// fp8 halves every byte-sized cost vs bf16: staging issues 32->16, LDS rows
// 256B->128B (frag reads b64), K-tiles 4->2 (barriers 8->4), FETCH ~halves.
// Non-scaled 16x16x32 fp8 MFMA = bf16 rate, operands consumed DIRECTLY from
// ds_read_b64 (r17 lesson: K=128 scaled form needs v8i32 packing -> VALU cost
// exceeds MFMA-issue savings when MfmaUtil is only ~30%).
__global__ __launch_bounds__(256, 4) void simloss_kernel(
    const unsigned char* __restrict__ zn,
    const int* __restrict__ labels,
    float* __restrict__ rowExpP,   /* [65][8192] */
    float* __restrict__ rowPosP)   /* [65][8192] */
{
    const int i = blockIdx.x;          // 0..63 row panel
    const int d = blockIdx.y;          // 0..32 band
    if (d == 32 && i >= 32) return;    // half-band: pair {i,i+32} once
    const int j = (i + d) & 63;        // col panel

    const int rb = i * BT;
    const int cb = j * BT;

    __shared__ __align__(16) char ldsS[32768];   // staging A(16K)+B(16K); tables overlay
    __shared__ int labRow[BT];
    __shared__ int labCol[BT];

    char* ldsA = ldsS;
    char* ldsB = ldsS + 16384;

    const int tid  = threadIdx.x;
    const int lane = tid & 63;
    const int wave = tid >> 6;           // 0..3
    const int wr = wave >> 1, wc = wave & 1;
    const int l15 = lane & 15, lg = lane >> 4;

    if (tid < BT)      labRow[tid]      = labels[(rb + tid) & (N_ROWS - 1)];
    else               labCol[tid - BT] = labels[(cb + tid - BT) & (N_ROWS - 1)];

    f32x4 acc[4][4];
    #pragma unroll
    for (int a = 0; a < 4; ++a)
        #pragma unroll
        for (int b = 0; b < 4; ++b) acc[a][b] = (f32x4){0.f, 0.f, 0.f, 0.f};

    #pragma unroll
    for (int kt = 0; kt < E_DIM / KT; ++kt) {   // 2 K-tiles of 128 fp8
        // stage 16KB/matrix: 128 rows x 128B; 1024 chunks of 16B, 4 its/thread;
        // linear LDS dest, pre-swizzled global source chunk = (pos ^ (row&7)).
        #pragma unroll
        for (int it = 0; it < 4; ++it) {
            const int idx = it * 256 + wave * 64 + lane;  // 16B chunk id 0..1023
            const int row = idx >> 3;                     // 0..127
            const int sch = (idx & 7) ^ (row & 7);
            gload_lds16(zn + (size_t)(rb + row) * E_DIM + kt * KT + sch * 16,
                        ldsA + (it * 256 + wave * 64) * 16);
            gload_lds16(zn + (size_t)(cb + row) * E_DIM + kt * KT + sch * 16,
                        ldsB + (it * 256 + wave * 64) * 16);
        }
        __syncthreads();

        #pragma unroll
        for (int ks = 0; ks < 4; ++ks) {       // K=32 per MFMA step
            i64 af[4], bfr[4];
            const int kc = ks * 4 + lg;        // 8B unit index in row, 0..15
            const int c  = kc >> 1, h = kc & 1;
            #pragma unroll
            for (int rf = 0; rf < 4; ++rf) {
                const int r = wr * 64 + rf * 16 + l15;
                af[rf] = *(const i64*)(ldsA + r * 128 + ((c ^ (r & 7)) << 4) + h * 8);
            }
            #pragma unroll
            for (int cf = 0; cf < 4; ++cf) {
                const int cc = wc * 64 + cf * 16 + l15;
                bfr[cf] = *(const i64*)(ldsB + cc * 128 + ((c ^ (cc & 7)) << 4) + h * 8);
            }
            #pragma unroll
            for (int rf = 0; rf < 4; ++rf)
                #pragma unroll
                for (int cf = 0; cf < 4; ++cf)
                    acc[rf][cf] = __builtin_amdgcn_mfma_f32_16x16x32_fp8_fp8(
                        af[rf], bfr[cf], acc[rf][cf], 0, 0, 0);
        }
        __syncthreads();
    }

    // ---- epilogue (r13-frozen): one sweep -> row table + col regs; pos pass ----
    const bool isDiag = (d == 0);
    const bool cross  = (i < 32) != (j < 32);

    float* tblRow = (float*)ldsS;            // [128][44] f32 = 22.5KB (overlay)
    float* tblCol = (float*)(ldsS + 22528);  // [128][12] f32 = 6KB

    int cl[4], clab[4];
    #pragma unroll
    for (int cf = 0; cf < 4; ++cf) {
        cl[cf]   = wc * 64 + cf * 16 + l15;
        clab[cf] = labCol[cl[cf]];
    }

    float colE[4] = {0.f, 0.f, 0.f, 0.f};
    float colP[4] = {0.f, 0.f, 0.f, 0.f};

    #pragma unroll
    for (int rf = 0; rf < 4; ++rf) {
        #pragma unroll
        for (int jj = 0; jj < 4; ++jj) {
            const int rloc = wr * 64 + rf * 16 + lg * 4 + jj;
            const int rlab = labRow[rloc];
            float rowE = 0.f;
            #pragma unroll
            for (int cf = 0; cf < 4; ++cf) {
                const float s = acc[rf][cf][jj];         // = sim * 10*log2(e)
                float e = __builtin_amdgcn_exp2f(s);
                if (isDiag && rloc == cl[cf]) e = 0.f;
                rowE += e;
                colE[cf] += e;
                if (cross && rlab == clab[cf]) colP[cf] += s;
            }
            tblRow[rloc * 44 + wc * 16 + l15] = rowE;
        }
    }
    #pragma unroll
    for (int cf = 0; cf < 4; ++cf)
        tblCol[cl[cf] * 12 + wr * 4 + lg] = colE[cf];

    __syncthreads();

    if (tid < 128) {
        const float* rp = tblRow + tid * 44;
        const int rot = (tid >> 3) & 7;
        float es = 0.f;
        #pragma unroll
        for (int c0 = 0; c0 < 8; ++c0) {
            const int ch = (c0 + rot) & 7;
            f32x4 v = *(const f32x4*)(rp + ch * 4);
            es += v[0] + v[1] + v[2] + v[3];
        }
        rowExpP[(size_t)d * TWO_N + rb + tid] = es;

        if (d > 0) {
            const float* cp = tblCol + tid * 12;
            f32x4 a = *(const f32x4*)(cp);
            f32x4 b = *(const f32x4*)(cp + 4);
            rowExpP[(size_t)(32 + d) * TWO_N + cb + tid] =
                a[0]+a[1]+a[2]+a[3] + b[0]+b[1]+b[2]+b[3];
        }
    }

    if (cross) {
        __syncthreads();
        #pragma unroll
        for (int rf = 0; rf < 4; ++rf) {
            #pragma unroll
            for (int jj = 0; jj < 4; ++jj) {
                const int rloc = wr * 64 + rf * 16 + lg * 4 + jj;
                const int rlab = labRow[rloc];
                float rowP = 0.f;
                #pragma unroll
                for (int cf = 0; cf < 4; ++cf)
                    if (rlab == clab[cf]) rowP += acc[rf][cf][jj];
                tblRow[rloc * 44 + wc * 16 + l15] = rowP;
            }
        }
        #pragma unroll
        for (int cf = 0; cf < 4; ++cf)
            tblCol[cl[cf] * 12 + wr * 4 + lg] = colP[cf];
        __syncthreads();
        if (tid < 128) {
            const float* rp = tblRow + tid * 44;
            const int rot = (tid >> 3) & 7;
            float ps = 0.f;
            #pragma unroll
            for (int c0 = 0; c0 < 8; ++c0) {
                const int ch = (c0 + rot) & 7;
                f32x4 v = *(const f32x4*)(rp + ch * 4);
                ps += v[0] + v[1] + v[2] + v[3];
            }
            rowPosP[(size_t)d * TWO_N + rb + tid] = ps;
            if (d > 0) {
                const float* cp = tblCol + tid * 12;
                f32x4 a = *(const f32x4*)(cp);
                f32x4 b = *(const f32x4*)(cp + 4);
                rowPosP[(size_t)(32 + d) * TWO_N + cb + tid] =
                    a[0]+a[1]+a[2]+a[3] + b[0]+b[1]+b[2]+b[3];
            }
        }
    } else {
        if (tid < 128) {
            rowPosP[(size_t)d * TWO_N + rb + tid] = 0.f;
            if (d > 0) rowPosP[(size_t)(32 + d) * TWO_N + cb + tid] = 0.f;
        }
    }

    // ---- d=32 mirror slots (tiles (j, j+32) for j>=32 are not dispatched) ----
    if (d == 32 && tid < 128) {
        rowExpP[(size_t)64 * TWO_N + rb + tid] = 0.f;
        rowExpP[(size_t)32 * TWO_N + cb + tid] = 0.f;
        rowPosP[(size_t)64 * TWO_N + rb + tid] = 0.f;
        rowPosP[(size_t)32 * TWO_N + cb + tid] = 0.f;
    }
}

// ---------------- finalize (merged): partials reduce + last-block scalar ----------------
__global__ __launch_bounds__(256) void fin_kernel(
    const float* __restrict__ rowExpP, const float* __restrict__ rowPosP,
    const int* __restrict__ labels, double* __restrict__ partial,
    int* __restrict__ cnt, float* __restrict__ out)
{
    __shared__ int hist[128];
    __shared__ double wsum[4];
    const int tid = threadIdx.x;
    if (tid < 128) hist[tid] = 0;
    __syncthreads();
    for (int idx = tid; idx < N_ROWS; idx += 256) atomicAdd(&hist[labels[idx]], 1);
    __syncthreads();

    const int r = blockIdx.x * 256 + tid;  // 0..8191 (grid = 32)
    float es = 0.f;
    #pragma unroll 5
    for (int s = 0; s < NSLOT; ++s) es += rowExpP[(size_t)s * TWO_N + r];
    float ps = 0.f;
    #pragma unroll 5
    for (int s = 0; s < NSLOT; ++s) ps += rowPosP[(size_t)s * TWO_N + r];

    const int lab = labels[r & (N_ROWS - 1)];
    // ps is scaled by 10*log2(e); 10*sim_sum = ps * ln(2)
    double g = ((double)ps * 0.6931471805599453 - (double)N_ROWS * log((double)es))
               / (2.0 * (double)hist[lab]);

    #pragma unroll
    for (int m = 32; m >= 1; m >>= 1) g += __shfl_xor(g, m);
    const int wave = tid >> 6, lane = tid & 63;
    if (lane == 0) wsum[wave] = g;
    __syncthreads();
    if (tid == 0) {
        partial[blockIdx.x] = wsum[0] + wsum[1] + wsum[2] + wsum[3];
        __threadfence();                        // 32 fences, post-traffic: cheap (r15-proven)
        const int t = atomicAdd(&cnt[0], 1);
        if (t == 31) {
            __threadfence();
            double tot = 0.0;
            for (int b = 0; b < 32; ++b) tot += partial[b];   // fixed order: deterministic
            out[0] = (float)(-tot / (double)TWO_N);
        }
    }
}

extern "C" void kernel_launch(void* const* d_in, const int* in_sizes, int n_in,
                              void* d_out, int out_size, void* d_ws, size_t ws_size,
                              hipStream_t stream) {
    const float* tab    = (const float*)d_in[0];
    const float* ts     = (const float*)d_in[1];
    const int*   labels = (const int*)d_in[2];

    char* ws = (char*)d_ws;
    unsigned char* zn = (unsigned char*)ws;                          // 2 MB fp8
    const size_t znBytes = (size_t)TWO_N * E_DIM;
    float* rowExpP = (float*)(ws + znBytes);                         // 2.13 MB [65][8192]
    float* rowPosP = rowExpP + (size_t)NSLOT * TWO_N;                // 2.13 MB [65][8192]
    double* partial = (double*)(rowPosP + (size_t)NSLOT * TWO_N);    // 256 B
    int* cnt = (int*)(partial + 32);                                 // 4 B

    prep_kernel<<<TWO_N / 4, 256, 0, stream>>>(tab, ts, zn, cnt);

    dim3 grid(64, 33);  // i fast (XCD = i%8, fixed A-set); d slow (fixed B-class/band)
    simloss_kernel<<<grid, 256, 0, stream>>>(zn, labels, rowExpP, rowPosP);

    fin_kernel<<<32, 256, 0, stream>>>(rowExpP, rowPosP, labels, partial, cnt, (float*)d_out);
}